// Round 4
// baseline (138.226 us; speedup 1.0000x reference)
//
#include <hip/hip_runtime.h>

#define HH 256
#define WW 256
#define BB 4
#define HW (HH*WW)
#define N_ITER 20
#define EPSV 1e-8f

#define FUSE 4
#define TILE 32
#define HALO (2*FUSE)            // 8
#define EXT  (TILE + 2*HALO)     // 48
#define EPAD 60                  // row stride in floats: 240B, 16B-aligned, 8-row bank cycle
#define COFF 4                   // data column offset: keeps edge reads in-bounds, preserves alignment
#define QX   (EXT/4)             // 12 quads per row
#define NTHR (EXT*QX)            // 576 threads = 9 waves

__device__ __forceinline__ float ldz(const float* __restrict__ p, int y, int x) {
    if ((unsigned)y < HH && (unsigned)x < WW) return p[y*WW + x];
    return 0.0f;
}
__device__ __forceinline__ float sobelXg(const float* __restrict__ p, int y, int x) {
    return -ldz(p,y-1,x-1) + ldz(p,y-1,x+1)
         - 2.0f*ldz(p,y,x-1) + 2.0f*ldz(p,y,x+1)
         - ldz(p,y+1,x-1) + ldz(p,y+1,x+1);
}
__device__ __forceinline__ float sobelYg(const float* __restrict__ p, int y, int x) {
    return -ldz(p,y-1,x-1) - 2.0f*ldz(p,y-1,x) - ldz(p,y-1,x+1)
          + ldz(p,y+1,x-1) + 2.0f*ldz(p,y+1,x) + ldz(p,y+1,x+1);
}

__global__ void tvl1_init(const float* __restrict__ xin, float* __restrict__ u,
                          float* __restrict__ p1, float* __restrict__ p2,
                          float* __restrict__ gx, float* __restrict__ gy,
                          float* __restrict__ rc) {
    int x = blockIdx.x*blockDim.x + threadIdx.x;
    int y = blockIdx.y*blockDim.y + threadIdx.y;
    int b = blockIdx.z;
    int idx = y*WW + x;
    int pb = b*2*HW;
    const float* im1 = xin + pb + HW;     // channel 1
    float i1 = im1[idx];
    rc[b*HW + idx] = i1 - xin[pb + idx];  // im1 - im0
    gx[b*HW + idx] = sobelXg(im1, y, x);
    gy[b*HW + idx] = sobelYg(im1, y, x);
    u[pb + idx] = 0.0f;  u[pb + HW + idx] = 0.0f;
    p1[pb + idx] = 0.0f; p1[pb + HW + idx] = 0.0f;
    p2[pb + idx] = 0.0f; p2[pb + HW + idx] = 0.0f;
}

// load row window: v[0..5] = s[y][COFF + x-1 .. COFF + x+4]  (x multiple of 4)
__device__ __forceinline__ void ldrow(const float (*__restrict__ s)[EPAD], int y, int x, float* v) {
    const float4 m = *(const float4*)&s[y][COFF + x];   // 16B-aligned
    v[0] = s[y][COFF + x - 1];
    v[1] = m.x; v[2] = m.y; v[3] = m.z; v[4] = m.w;
    v[5] = s[y][COFF + x + 4];
}

template<int LAST>
__global__ __launch_bounds__(NTHR)
void tvl1_fused(float* __restrict__ u,
                float* __restrict__ p1, float* __restrict__ p2,
                const float* __restrict__ gxc, const float* __restrict__ gyc,
                const float* __restrict__ rcc,
                const float* __restrict__ lam, const float* __restrict__ tau,
                const float* __restrict__ the) {
    __shared__ float su0[EXT][EPAD], su1[EXT][EPAD];
    __shared__ float sp10[EXT][EPAD], sp11[EXT][EPAD];
    __shared__ float sp20[EXT][EPAD], sp21[EXT][EPAD];

    const int tid = threadIdx.x;
    const int qy = tid / QX;                 // 0..47 (compile-time divisor)
    const int qx = (tid - qy*QX) * 4;        // 0,4,...,44
    const int b  = blockIdx.z;
    const int ox = blockIdx.x*TILE - HALO;
    const int oy = blockIdx.y*TILE - HALO;
    const int pb = b*2*HW, cb = b*HW;
    const float theta = the[0];
    const float tl = theta * lam[0];
    const float r = tau[0] / theta;

    const int gyy = oy + qy;
    const int gxx = ox + qx;
    // quads are 4-aligned in x and W=256 is a multiple of 4 -> a quad is never partially in-image
    const bool inq = ((unsigned)gyy < HH) && ((unsigned)gxx < WW);
    const int gi = gyy*WW + gxx;

    float ru0[4], ru1[4], rp10[4], rp11[4], rp20[4], rp21[4];
    float rgx[4], rgy[4], rrc[4];
    const float4 z4 = make_float4(0.f, 0.f, 0.f, 0.f);

    // ---- stage: registers hold this quad's state; LDS holds neighbor-visible copies ----
    *(float4*)ru0  = inq ? *(const float4*)&u  [pb + gi]      : z4;
    *(float4*)ru1  = inq ? *(const float4*)&u  [pb + HW + gi] : z4;
    *(float4*)rp10 = inq ? *(const float4*)&p1 [pb + gi]      : z4;
    *(float4*)rp11 = inq ? *(const float4*)&p1 [pb + HW + gi] : z4;
    *(float4*)rp20 = inq ? *(const float4*)&p2 [pb + gi]      : z4;
    *(float4*)rp21 = inq ? *(const float4*)&p2 [pb + HW + gi] : z4;
    *(float4*)rgx  = inq ? *(const float4*)&gxc[cb + gi]      : z4;
    *(float4*)rgy  = inq ? *(const float4*)&gyc[cb + gi]      : z4;
    *(float4*)rrc  = inq ? *(const float4*)&rcc[cb + gi]      : z4;

    *(float4*)&su0 [qy][COFF+qx] = *(float4*)ru0;
    *(float4*)&su1 [qy][COFF+qx] = *(float4*)ru1;
    *(float4*)&sp10[qy][COFF+qx] = *(float4*)rp10;
    *(float4*)&sp11[qy][COFF+qx] = *(float4*)rp11;
    *(float4*)&sp20[qy][COFF+qx] = *(float4*)rp20;
    *(float4*)&sp21[qy][COFF+qx] = *(float4*)rp21;
    __syncthreads();

    const int NH = LAST ? (2*FUSE - 1) : (2*FUSE);
    for (int h = 0; h < NH; ++h) {
        const int lo = h + 1, hi = EXT - 1 - h;
        const bool rowact = (qy >= lo) && (qy < hi);
        const bool quadact = rowact && (qx + 3 >= lo) && (qx < hi) && inq;
        if ((h & 1) == 0) {
            // ---- u half-step: pointwise u from regs, p neighbors from LDS (p frozen) ----
            if (quadact) {
                float A0[6], B0[6], C0[6], D0[6], E0[6];
                float A1[6], B1[6], C1[6], D1[6], E1[6];
                ldrow(sp10, qy-1, qx, A0); ldrow(sp10, qy, qx, B0); ldrow(sp10, qy+1, qx, C0);
                ldrow(sp20, qy-1, qx, D0); ldrow(sp20, qy+1, qx, E0);   // SBY: middle row weight 0
                ldrow(sp11, qy-1, qx, A1); ldrow(sp11, qy, qx, B1); ldrow(sp11, qy+1, qx, C1);
                ldrow(sp21, qy-1, qx, D1); ldrow(sp21, qy+1, qx, E1);
                #pragma unroll
                for (int j = 0; j < 4; ++j) {
                    float g_x = rgx[j], g_y = rgy[j];
                    float ng  = g_x*g_x + g_y*g_y + EPSV;
                    float rho = rrc[j] + g_x*ru0[j] + g_y*ru1[j];
                    float th  = tl * ng;
                    float sgn = (rho > 0.f) ? 1.f : ((rho < 0.f) ? -1.f : 0.f);
                    float d   = (fabsf(rho) < th) ? (rho / ng) : (tl * sgn);
                    float div0 = (-A0[j] + A0[j+2] - 2.f*B0[j] + 2.f*B0[j+2] - C0[j] + C0[j+2])
                               + (-D0[j] - 2.f*D0[j+1] - D0[j+2] + E0[j] + 2.f*E0[j+1] + E0[j+2]);
                    float div1 = (-A1[j] + A1[j+2] - 2.f*B1[j] + 2.f*B1[j+2] - C1[j] + C1[j+2])
                               + (-D1[j] - 2.f*D1[j+1] - D1[j+2] + E1[j] + 2.f*E1[j+1] + E1[j+2]);
                    bool act = ((unsigned)(qx + j - lo) < (unsigned)(hi - lo));
                    float n0 = ru0[j] - d*g_x + theta*div0;
                    float n1 = ru1[j] - d*g_y + theta*div1;
                    ru0[j] = act ? n0 : ru0[j];
                    ru1[j] = act ? n1 : ru1[j];
                }
                *(float4*)&su0[qy][COFF+qx] = *(float4*)ru0;
                *(float4*)&su1[qy][COFF+qx] = *(float4*)ru1;
            }
        } else {
            // ---- p half-step: pointwise p from regs, u neighbors from LDS (u frozen) ----
            if (quadact) {
                float A0[6], B0[6], C0[6], A1[6], B1[6], C1[6];
                ldrow(su0, qy-1, qx, A0); ldrow(su0, qy, qx, B0); ldrow(su0, qy+1, qx, C0);
                ldrow(su1, qy-1, qx, A1); ldrow(su1, qy, qx, B1); ldrow(su1, qy+1, qx, C1);
                #pragma unroll
                for (int j = 0; j < 4; ++j) {
                    float g1x = -A0[j] + A0[j+2] - 2.f*B0[j] + 2.f*B0[j+2] - C0[j] + C0[j+2];
                    float g1y = -A0[j] - 2.f*A0[j+1] - A0[j+2] + C0[j] + 2.f*C0[j+1] + C0[j+2];
                    float g2x = -A1[j] + A1[j+2] - 2.f*B1[j] + 2.f*B1[j+2] - C1[j] + C1[j+2];
                    float g2y = -A1[j] - 2.f*A1[j+1] - A1[j+2] + C1[j] + 2.f*C1[j+1] + C1[j+2];
                    float inv1 = 1.f / (1.f + r*(fabsf(g1x) + fabsf(g1y)));
                    float inv2 = 1.f / (1.f + r*(fabsf(g2x) + fabsf(g2y)));
                    bool act = ((unsigned)(qx + j - lo) < (unsigned)(hi - lo));
                    float n10 = (rp10[j] + r*g1x) * inv1;
                    float n11 = (rp11[j] + r*g1y) * inv1;
                    float n20 = (rp20[j] + r*g2x) * inv2;
                    float n21 = (rp21[j] + r*g2y) * inv2;
                    rp10[j] = act ? n10 : rp10[j];
                    rp11[j] = act ? n11 : rp11[j];
                    rp20[j] = act ? n20 : rp20[j];
                    rp21[j] = act ? n21 : rp21[j];
                }
                *(float4*)&sp10[qy][COFF+qx] = *(float4*)rp10;
                *(float4*)&sp11[qy][COFF+qx] = *(float4*)rp11;
                *(float4*)&sp20[qy][COFF+qx] = *(float4*)rp20;
                *(float4*)&sp21[qy][COFF+qx] = *(float4*)rp21;
            }
        }
        __syncthreads();
    }

    // ---- write back interior straight from registers ----
    if (qy >= HALO && qy < HALO+TILE && qx >= HALO && qx < HALO+TILE) {
        int go = (oy + qy)*WW + (ox + qx);       // 16B-aligned (ox+qx multiple of 4)
        *(float4*)&u[pb + go]      = *(float4*)ru0;
        *(float4*)&u[pb + HW + go] = *(float4*)ru1;
        if (!LAST) {
            *(float4*)&p1[pb + go]      = *(float4*)rp10;
            *(float4*)&p1[pb + HW + go] = *(float4*)rp11;
            *(float4*)&p2[pb + go]      = *(float4*)rp20;
            *(float4*)&p2[pb + HW + go] = *(float4*)rp21;
        }
    }
}

extern "C" void kernel_launch(void* const* d_in, const int* in_sizes, int n_in,
                              void* d_out, int out_size, void* d_ws, size_t ws_size,
                              hipStream_t stream) {
    const float* xin = (const float*)d_in[0];
    const float* lam = (const float*)d_in[1];
    const float* tau = (const float*)d_in[2];
    const float* the = (const float*)d_in[3];
    float* u = (float*)d_out;              // u lives in d_out (B,2,H,W)

    float* ws = (float*)d_ws;
    float* p1 = ws;                        // B*2*HW
    float* p2 = ws + (size_t)BB*2*HW;      // B*2*HW
    float* gx = ws + (size_t)2*BB*2*HW;    // B*HW
    float* gy = gx + (size_t)BB*HW;        // B*HW
    float* rc = gy + (size_t)BB*HW;        // B*HW

    {
        dim3 blk(64, 4, 1);
        dim3 grd(WW/64, HH/4, BB);
        tvl1_init<<<grd, blk, 0, stream>>>(xin, u, p1, p2, gx, gy, rc);
    }

    dim3 blk(NTHR, 1, 1);
    dim3 grd(WW/TILE, HH/TILE, BB);        // 8 x 8 x 4 = 256 blocks
    const int NLAUNCH = N_ITER / FUSE;     // 5
    for (int j = 0; j < NLAUNCH; ++j) {
        if (j < NLAUNCH - 1)
            tvl1_fused<0><<<grd, blk, 0, stream>>>(u, p1, p2, gx, gy, rc, lam, tau, the);
        else
            tvl1_fused<1><<<grd, blk, 0, stream>>>(u, p1, p2, gx, gy, rc, lam, tau, the);
    }
}